// Round 1
// baseline (65.983 us; speedup 1.0000x reference)
//
#include <hip/hip_runtime.h>
#include <hip/hip_bf16.h>
#include <stdint.h>

// VQ: z (32,256,32,32) f32 NCHW, codebook (1024,256) f32
// out: z_q (8388608 f32, NCHW) + commit_loss (1 f32)

#define NPOS   32768
#define NCODE  1024
#define DIM    256
#define BLKPOS 64
#define NBLK   (NPOS / BLKPOS)      // 512
#define CHUNK  32                   // codes per staged chunk
#define NCHUNK (NCODE / CHUNK)      // 32

// ws layout
#define WS_CNORM_OFF 0
#define WS_CB_OFF    4096
#define WS_PART_OFF  (4096 + 512 * 1024)

typedef float f32x4 __attribute__((ext_vector_type(4)));
typedef short s16x8 __attribute__((ext_vector_type(8)));

static __device__ __forceinline__ unsigned short f2bf(float f) {
    unsigned u = __builtin_bit_cast(unsigned, f);
    u = (u + 0x7fffu + ((u >> 16) & 1u)) >> 16;
    return (unsigned short)u;
}

// ---------------- K0: codebook norms + bf16 swizzled copy ----------------
__global__ __launch_bounds__(64) void k0_prep(const float* __restrict__ cb,
                                              float* __restrict__ cnorm,
                                              unsigned char* __restrict__ cbswz) {
    const int code = blockIdx.x;
    const int l = threadIdx.x;
    const float4 v = ((const float4*)cb)[code * 64 + l];
    float nrm = v.x * v.x + v.y * v.y + v.z * v.z + v.w * v.w;
    #pragma unroll
    for (int off = 1; off < 64; off <<= 1) nrm += __shfl_xor(nrm, off);
    if (l == 0) cnorm[code] = nrm;
    ushort4 h;
    h.x = f2bf(v.x); h.y = f2bf(v.y); h.z = f2bf(v.z); h.w = f2bf(v.w);
    // swizzle: byte offset within 512B row XORed by (row&7)<<4 (16B granules)
    const int byteoff = (l * 8) ^ ((code & 7) << 4);
    *(ushort4*)(cbswz + code * 512 + byteoff) = h;
}

// ---------------- staging helper: 16KB chunk -> LDS (linear) ----------------
static __device__ __forceinline__ void stage_chunk(const unsigned char* __restrict__ cbswz,
                                                   unsigned char* cbbuf, int chunk, int t) {
    const unsigned char* src = cbswz + chunk * 16384;
    unsigned char* dst = cbbuf + (chunk & 1) * 16384;
    const int w = t >> 6;
    const int l = t & 63;
    #pragma unroll
    for (int i = 0; i < 8; ++i) {
        const int off = (i * 2 + w) * 1024;
        __builtin_amdgcn_global_load_lds(
            (const __attribute__((address_space(1))) unsigned int*)(src + off + l * 16),
            (__attribute__((address_space(3))) unsigned int*)(dst + off),
            16, 0, 0);
    }
}

// ---------------- K1: fused argmin + gather + loss partials ----------------
__global__ __launch_bounds__(128, 2) void k1_main(const float* __restrict__ z,
                                                  const float* __restrict__ cbf,
                                                  const float* __restrict__ cnorm,
                                                  const unsigned char* __restrict__ cbswz,
                                                  float* __restrict__ out,
                                                  float* __restrict__ part) {
    // union region: [0,32768) cb double-buffer | [0,33024) zq staging f32[32][258]
    __shared__ __align__(16) unsigned char smem[33024 + 256 + 32];
    unsigned char* cbbuf = smem;
    float* zqbuf = (float*)smem;                       // [32][258]
    unsigned* idxl = (unsigned*)(smem + 33024);        // 64 indices
    float* red = (float*)(smem + 33024 + 256);         // 2 wave partials

    const int t = threadIdx.x;
    const int w = t >> 6;          // wave 0/1 -> pos halves
    const int l = t & 63;
    const int b = blockIdx.x;
    const int bimg = b >> 4;                 // image index
    const int hw0 = (b & 15) << 6;           // hw base within image
    const float* zp = z + bimg * 262144 + hw0;

    stage_chunk(cbswz, cbbuf, 0, t);

    // ---- z gather -> bf16 B-fragments in registers (+ sum z^2 in f32) ----
    const int col = l & 15;   // pos within fragment (B col / D col)
    const int g = l >> 4;     // k-group
    float z2 = 0.f;
    s16x8 zf[2][8];
    #pragma unroll
    for (int pf = 0; pf < 2; ++pf) {
        const int p = w * 32 + pf * 16 + col;
        #pragma unroll
        for (int ks = 0; ks < 8; ++ks) {
            const float* src = zp + (ks * 32 + g * 8) * 1024 + p;
            s16x8 f;
            #pragma unroll
            for (int j = 0; j < 8; ++j) {
                const float v = src[j * 1024];
                z2 += v * v;
                f[j] = (short)f2bf(v);
            }
            zf[pf][ks] = f;
        }
    }

    const int swz = (l & 7) << 4;
    float minS[2] = {1e30f, 1e30f};
    unsigned minC[2] = {0u, 0u};

    for (int c = 0; c < NCHUNK; ++c) {
        __syncthreads();                       // chunk c staged (vmcnt drain), prev buf reads done
        if (c + 1 < NCHUNK) stage_chunk(cbswz, cbbuf, c + 1, t);
        const unsigned char* buf = cbbuf + (c & 1) * 16384;
        const int cbase = c * CHUNK;
        #pragma unroll
        for (int cf = 0; cf < 2; ++cf) {
            s16x8 a[8];
            const unsigned char* rowp = buf + (cf * 16 + col) * 512;
            #pragma unroll
            for (int ks = 0; ks < 8; ++ks)
                a[ks] = *(const s16x8*)(rowp + ((ks * 64 + g * 16) ^ swz));
            float cn[4];
            #pragma unroll
            for (int r = 0; r < 4; ++r)
                cn[r] = cnorm[cbase + cf * 16 + g * 4 + r];
            #pragma unroll
            for (int pf = 0; pf < 2; ++pf) {
                f32x4 acc = {0.f, 0.f, 0.f, 0.f};
                #pragma unroll
                for (int ks = 0; ks < 8; ++ks)
                    acc = __builtin_amdgcn_mfma_f32_16x16x32_bf16(a[ks], zf[pf][ks], acc, 0, 0, 0);
                #pragma unroll
                for (int r = 0; r < 4; ++r) {
                    const float s = fmaf(-2.f, acc[r], cn[r]);
                    const unsigned code = (unsigned)(cbase + cf * 16 + g * 4 + r);
                    if (s < minS[pf]) { minS[pf] = s; minC[pf] = code; }
                }
            }
        }
    }

    // merge argmin across the 4 lane-groups (lanes sharing the same pos-col)
    #pragma unroll
    for (int pf = 0; pf < 2; ++pf) {
        #pragma unroll
        for (int off = 16; off < 64; off <<= 1) {
            const float oS = __shfl_xor(minS[pf], off);
            const unsigned oC = __shfl_xor(minC[pf], off);
            if (oS < minS[pf] || (oS == minS[pf] && oC < minC[pf])) {
                minS[pf] = oS; minC[pf] = oC;
            }
        }
    }

    // loss partial: sum(z^2) + sum_pos minS   (minS duplicated x4 across groups)
    float tl = z2 + 0.25f * (minS[0] + minS[1]);
    #pragma unroll
    for (int off = 1; off < 64; off <<= 1) tl += __shfl_xor(tl, off);
    if (l == 0) red[w] = tl;
    if (l < 16) {
        idxl[w * 32 + l] = minC[0];
        idxl[w * 32 + 16 + l] = minC[1];
    }
    __syncthreads();
    if (t == 0) part[b] = red[0] + red[1];

    // ---- fused z_q output: codebook rows -> LDS transpose -> NCHW stores ----
    const int obase = bimg * 262144 + hw0;
    for (int h = 0; h < 2; ++h) {
        __syncthreads();   // zqbuf (overlaps cbbuf) free for reuse
        #pragma unroll
        for (int i = 0; i < 16; ++i) {
            const int flat = i * 128 + t;           // [0,2048)
            const int p = flat >> 6;                // pos 0..31
            const int q = flat & 63;                // float4 index in row
            const unsigned code = idxl[h * 32 + p];
            const float4 v = ((const float4*)cbf)[code * 64 + q];
            float2* dst = (float2*)(zqbuf + p * 258 + q * 4);
            dst[0] = make_float2(v.x, v.y);
            dst[1] = make_float2(v.z, v.w);
        }
        __syncthreads();
        const int p = t & 31;
        const int c0 = t >> 5;
        float* ob = out + obase + h * 32 + p;
        #pragma unroll
        for (int cc = 0; cc < 64; ++cc) {
            const int ch = c0 + cc * 4;
            ob[ch * 1024] = zqbuf[p * 258 + ch];
        }
    }
}

// ---------------- K2: deterministic final reduce -> loss ----------------
__global__ __launch_bounds__(256) void k2_fin(const float* __restrict__ part,
                                              float* __restrict__ out) {
    __shared__ float red[256];
    const int t = threadIdx.x;
    red[t] = part[t] + part[t + 256];
    __syncthreads();
    #pragma unroll
    for (int off = 128; off > 0; off >>= 1) {
        if (t < off) red[t] += red[t + off];
        __syncthreads();
    }
    if (t == 0) out[8388608] = 1.25f * red[0] / 8388608.f;
}

extern "C" void kernel_launch(void* const* d_in, const int* in_sizes, int n_in,
                              void* d_out, int out_size, void* d_ws, size_t ws_size,
                              hipStream_t stream) {
    const float* z  = (const float*)d_in[0];
    const float* cb = (const float*)d_in[1];
    float* out = (float*)d_out;
    unsigned char* ws = (unsigned char*)d_ws;
    float* cnorm = (float*)(ws + WS_CNORM_OFF);
    unsigned char* cbswz = ws + WS_CB_OFF;
    float* part = (float*)(ws + WS_PART_OFF);

    hipLaunchKernelGGL(k0_prep, dim3(NCODE), dim3(64), 0, stream, cb, cnorm, cbswz);
    hipLaunchKernelGGL(k1_main, dim3(NBLK), dim3(128), 0, stream,
                       z, cb, cnorm, cbswz, out, part);
    hipLaunchKernelGGL(k2_fin, dim3(1), dim3(256), 0, stream, part, out);
}

// Round 2
// 57.898 us; speedup vs baseline: 1.1396x; 1.1396x over previous
//
#include <hip/hip_runtime.h>
#include <hip/hip_bf16.h>
#include <stdint.h>

// VQ: z (32,256,32,32) f32 NCHW, codebook (1024,256) f32
// out: z_q (8388608 f32, NCHW) + commit_loss (1 f32 at out[8388608])
//
// Strategy: codebook pre-converted (k0) to bf16 MFMA-fragment order, scaled by -2,
// in ws. k1: 256 blocks x 256 thr; each wave holds 32 positions' z as bf16 B-frags
// in registers; streams the fragment-ordered codebook straight from L2/L1 with
// register double-buffering (no LDS, no vmcnt-draining barriers in the main loop).
// Argmin folded into an encoded float min: (S & ~0x3FF) | code.

#define NPOS   32768
#define NCODE  1024
#define DIM    256
#define NCHUNK 32                   // chunks of 32 codes

#define WS_CNORM_OFF 0
#define WS_CB_OFF    4096
#define WS_PART_OFF  (4096 + 1024 * 512)   // 512KB cbfrag

typedef float f32x4 __attribute__((ext_vector_type(4)));
typedef short s16x8 __attribute__((ext_vector_type(8)));

static __device__ __forceinline__ unsigned short f2bf(float f) {
    unsigned u = __builtin_bit_cast(unsigned, f);
    u = (u + 0x7fffu + ((u >> 16) & 1u)) >> 16;
    return (unsigned short)u;
}

// ---------------- K0: cnorm + (-2*codebook) bf16 fragment-ordered ----------------
// cbfrag unit u = ((chunk*2 + cf)*8 + ks)*64 + lane, lane holds
// A[row = cf*16 + (lane&15)][k = ks*32 + (lane>>4)*8 + j], j=0..7, value -2*cb.
__global__ __launch_bounds__(64) void k0_prep(const float* __restrict__ cb,
                                              float* __restrict__ cnorm,
                                              s16x8* __restrict__ cbfrag) {
    const int code = blockIdx.x;
    const int l = threadIdx.x;
    const float4* cb4 = (const float4*)cb;
    const float4 v = cb4[code * 64 + l];
    float nrm = v.x * v.x + v.y * v.y + v.z * v.z + v.w * v.w;
    #pragma unroll
    for (int off = 1; off < 64; off <<= 1) nrm += __shfl_xor(nrm, off);
    if (l == 0) cnorm[code] = nrm;
    if (l < 32) {
        // lane l supplies elements k = l*8 .. l*8+7  (ks = l>>2, g = l&3)
        const float4 x0 = cb4[code * 64 + l * 2];
        const float4 x1 = cb4[code * 64 + l * 2 + 1];
        s16x8 f;
        f[0] = (short)f2bf(-2.f * x0.x); f[1] = (short)f2bf(-2.f * x0.y);
        f[2] = (short)f2bf(-2.f * x0.z); f[3] = (short)f2bf(-2.f * x0.w);
        f[4] = (short)f2bf(-2.f * x1.x); f[5] = (short)f2bf(-2.f * x1.y);
        f[6] = (short)f2bf(-2.f * x1.z); f[7] = (short)f2bf(-2.f * x1.w);
        const int cc = code >> 5, cf = (code >> 4) & 1, r16 = code & 15;
        const int ks = l >> 2, g = l & 3;
        cbfrag[((cc * 2 + cf) * 8 + ks) * 64 + g * 16 + r16] = f;
    }
}

// ---------------- K1: fused argmin + gather + loss partials ----------------
__global__ __launch_bounds__(256, 1) void k1_main(const float* __restrict__ z,
                                                  const float* __restrict__ cbf,
                                                  const float* __restrict__ cnorm,
                                                  const s16x8* __restrict__ cbfrag,
                                                  float* __restrict__ out,
                                                  float* __restrict__ part) {
    __shared__ __align__(16) float zqbuf[32 * 260];
    __shared__ unsigned idxl[128];
    __shared__ float red[4];

    const int t = threadIdx.x;
    const int w = t >> 6, l = t & 63;
    const int col = l & 15, g = l >> 4;
    const int gc4 = g * 4;
    const int b = blockIdx.x;
    const int bimg = b >> 3;
    const int hw0 = (b & 7) << 7;         // 128 positions per block
    const float* zp = z + bimg * 262144 + hw0;

    // ---- z -> bf16 B-fragments in registers (+ sum z^2 in f32) ----
    float z2 = 0.f;
    s16x8 zf[2][8];
    #pragma unroll
    for (int pf = 0; pf < 2; ++pf) {
        const int p = w * 32 + pf * 16 + col;
        #pragma unroll
        for (int ks = 0; ks < 8; ++ks) {
            const float* src = zp + (ks * 32 + g * 8) * 1024 + p;
            s16x8 f;
            #pragma unroll
            for (int j = 0; j < 8; ++j) {
                const float v = src[j * 1024];
                z2 += v * v;
                f[j] = (short)f2bf(v);
            }
            zf[pf][ks] = f;
        }
    }

    float menc[2];
    menc[0] = __builtin_bit_cast(float, 0x7F7FFC00u);
    menc[1] = __builtin_bit_cast(float, 0x7F7FFC00u);

    s16x8 A0[16], A1[16];
    {
        const s16x8* p0 = cbfrag + l;
        #pragma unroll
        for (int u = 0; u < 16; ++u) A0[u] = p0[u * 64];
    }

#define BODY(CUR, NXT, c) do {                                                   \
    if ((c) + 1 < NCHUNK) {                                                      \
        const s16x8* pn = cbfrag + ((c) + 1) * 1024 + l;                         \
        _Pragma("unroll") for (int u = 0; u < 16; ++u) NXT[u] = pn[u * 64];      \
    }                                                                            \
    _Pragma("unroll") for (int cf = 0; cf < 2; ++cf) {                           \
        const f32x4 cn = *(const f32x4*)(cnorm + (c) * 32 + cf * 16 + gc4);      \
        _Pragma("unroll") for (int pf = 0; pf < 2; ++pf) {                       \
            f32x4 acc = {0.f, 0.f, 0.f, 0.f};                                    \
            _Pragma("unroll") for (int ks = 0; ks < 8; ++ks)                     \
                acc = __builtin_amdgcn_mfma_f32_16x16x32_bf16(                   \
                        CUR[cf * 8 + ks], zf[pf][ks], acc, 0, 0, 0);             \
            _Pragma("unroll") for (int r = 0; r < 4; ++r) {                      \
                const float s = acc[r] + cn[r];                                  \
                const unsigned e = (__builtin_bit_cast(unsigned, s)              \
                                    & 0xFFFFFC00u)                               \
                                   | (unsigned)((c) * 32 + cf * 16 + gc4 + r);   \
                menc[pf] = fminf(menc[pf], __builtin_bit_cast(float, e));        \
            }                                                                    \
        }                                                                        \
    }                                                                            \
    __builtin_amdgcn_s_barrier();                                                \
} while (0)

    #pragma unroll 1
    for (int c2 = 0; c2 < NCHUNK; c2 += 2) {
        BODY(A0, A1, c2);
        BODY(A1, A0, c2 + 1);
    }
#undef BODY

    // merge encoded argmin across the 4 g-groups sharing each position column
    #pragma unroll
    for (int pf = 0; pf < 2; ++pf) {
        menc[pf] = fminf(menc[pf], __shfl_xor(menc[pf], 16));
        menc[pf] = fminf(menc[pf], __shfl_xor(menc[pf], 32));
    }
    const unsigned e0 = __builtin_bit_cast(unsigned, menc[0]);
    const unsigned e1 = __builtin_bit_cast(unsigned, menc[1]);
    const float s0 = __builtin_bit_cast(float, e0 & 0xFFFFFC00u);
    const float s1 = __builtin_bit_cast(float, e1 & 0xFFFFFC00u);

    float tl = z2 + 0.25f * (s0 + s1);   // minS duplicated x4 across g-groups
    #pragma unroll
    for (int off = 1; off < 64; off <<= 1) tl += __shfl_xor(tl, off);
    if (l == 0) red[w] = tl;
    if (l < 16) {
        idxl[w * 32 + l]      = e0 & 0x3FFu;
        idxl[w * 32 + 16 + l] = e1 & 0x3FFu;
    }
    __syncthreads();
    if (t == 0) part[b] = red[0] + red[1] + red[2] + red[3];

    // ---- z_q epilogue: codebook rows -> LDS transpose -> coalesced NCHW ----
    const float4* cb4 = (const float4*)cbf;
    for (int h = 0; h < 4; ++h) {
        if (h) __syncthreads();
        #pragma unroll
        for (int i = 0; i < 8; ++i) {
            const int flat = i * 256 + t;        // [0,2048)
            const int p = flat >> 6;             // pos 0..31
            const int q = flat & 63;             // float4 index
            const unsigned code = idxl[h * 32 + p];
            *(float4*)&zqbuf[p * 260 + q * 4] = cb4[code * 64 + q];
        }
        __syncthreads();
        const int p = t & 31, c0 = t >> 5;
        float* ob = out + bimg * 262144 + hw0 + h * 32 + p;
        #pragma unroll
        for (int cc = 0; cc < 32; ++cc) {
            const int ch = c0 + cc * 8;
            ob[ch * 1024] = zqbuf[p * 260 + ch];
        }
    }
}

// ---------------- K2: deterministic final reduce -> loss ----------------
__global__ __launch_bounds__(256) void k2_fin(const float* __restrict__ part,
                                              float* __restrict__ out) {
    __shared__ float red[256];
    const int t = threadIdx.x;
    red[t] = part[t];
    __syncthreads();
    #pragma unroll
    for (int off = 128; off > 0; off >>= 1) {
        if (t < off) red[t] += red[t + off];
        __syncthreads();
    }
    if (t == 0) out[8388608] = 1.25f * red[0] / 8388608.f;
}

extern "C" void kernel_launch(void* const* d_in, const int* in_sizes, int n_in,
                              void* d_out, int out_size, void* d_ws, size_t ws_size,
                              hipStream_t stream) {
    const float* z  = (const float*)d_in[0];
    const float* cb = (const float*)d_in[1];
    float* out = (float*)d_out;
    unsigned char* ws = (unsigned char*)d_ws;
    float* cnorm = (float*)(ws + WS_CNORM_OFF);
    s16x8* cbfrag = (s16x8*)(ws + WS_CB_OFF);
    float* part = (float*)(ws + WS_PART_OFF);

    hipLaunchKernelGGL(k0_prep, dim3(NCODE), dim3(64), 0, stream, cb, cnorm, cbfrag);
    hipLaunchKernelGGL(k1_main, dim3(256), dim3(256), 0, stream,
                       z, cb, cnorm, cbfrag, out, part);
    hipLaunchKernelGGL(k2_fin, dim3(1), dim3(256), 0, stream, part, out);
}